// Round 4
// baseline (1850.471 us; speedup 1.0000x reference)
//
#include <hip/hip_runtime.h>
#include <hip/hip_bf16.h>
#include <cstdint>
#include <cstddef>

#define NB 32
#define NS 4096
#define NH 512
#define NK 1024   // 2H

typedef __attribute__((ext_vector_type(8))) short short8;
typedef __attribute__((ext_vector_type(4))) float f32x4;

__device__ __forceinline__ unsigned short f2bf_s(float f) {
  union { float f; unsigned u; } x; x.f = f;
  unsigned r = x.u + 0x7fffu + ((x.u >> 16) & 1u);   // RNE bf16
  return (unsigned short)(r >> 16);
}

__device__ __forceinline__ unsigned pk2(float lo, float hi) {
  __hip_bfloat162 h = __float22bfloat162_rn(float2{lo, hi});
  union { __hip_bfloat162 h; unsigned u; } c; c.h = h;
  return c.u;
}

__device__ __forceinline__ void gload16(const void* g, void* l) {
  __builtin_amdgcn_global_load_lds(
      (const __attribute__((address_space(1))) unsigned int*)g,
      (__attribute__((address_space(3))) unsigned int*)l, 16, 0, 0);
}

// ---- kernel 1: pack Ua [512 n][1024 k] f32 -> bf16, pre-swizzled LDS-linear order ----
// layout: [bn(2)][kc(16)][chunk c(2048) of 16B]; c: nloc=c>>3, k16=(c&7)^(nloc&7)
__global__ void k_ua_pack(const float* __restrict__ ua, unsigned short* __restrict__ out) {
  int t = blockIdx.x * 256 + threadIdx.x;   // 65536 chunks
  int c = t & 2047;
  int kc = (t >> 11) & 15;
  int bn = t >> 15;
  int nloc = c >> 3;
  int k16 = (c & 7) ^ (nloc & 7);
  const float* src = ua + (size_t)(bn * 256 + nloc) * NK + kc * 64 + k16 * 8;
  float4 a = *(const float4*)src;
  float4 b2 = *(const float4*)(src + 4);
  ushort4 o0, o1;
  o0.x = f2bf_s(a.x);  o0.y = f2bf_s(a.y);  o0.z = f2bf_s(a.z);  o0.w = f2bf_s(a.w);
  o1.x = f2bf_s(b2.x); o1.y = f2bf_s(b2.y); o1.z = f2bf_s(b2.z); o1.w = f2bf_s(b2.w);
  ushort4* dst = (ushort4*)(out + (size_t)t * 8);
  dst[0] = o0; dst[1] = o1;
}

// ---- kernel 2: qproj[b][h] = query[b]·Wa_w[h] + Wa_b[h] + Ua_b[h] ----
__global__ void k_qproj(const float* __restrict__ q, const float* __restrict__ ww,
                        const float* __restrict__ wb, const float* __restrict__ ub,
                        float* __restrict__ qp) {
  int b = blockIdx.y;
  int h = blockIdx.x * 128 + threadIdx.x;
  const float* qr = q + b * NH;
  const float* wr = ww + h * NH;
  float acc = 0.f;
  for (int k = 0; k < NH; k += 4) {
    float4 a = *(const float4*)(qr + k);
    float4 c = *(const float4*)(wr + k);
    acc += a.x * c.x + a.y * c.y + a.z * c.z + a.w * c.w;
  }
  qp[b * NH + h] = acc + wb[h] + ub[h];
}

// ---- kernel 3: scores partials, 256x256 tile, single-buffered LDS, 2 blocks/CU ----
// grid (16 sblk, 2 bn, 32 b), 512 thr = 8 waves = 2 rg x 4 cg, wave tile 128x64.
// Per kc: bar -> {issue B gload_lds, cvt+write A} -> bar(drain) -> {issue A(kc+1), 64 MFMA}.
// Inter-block overlap (2 blocks/CU) hides the stage+drain under the other block's MFMA.
__global__ __launch_bounds__(512, 4)
void k_scores4(const float* __restrict__ keys, const unsigned short* __restrict__ uapk,
               const float* __restrict__ qproj, const float* __restrict__ vaw,
               float* __restrict__ scores_part) {
  __shared__ alignas(16) unsigned short Albuf[256 * 64];  // 32KB
  __shared__ alignas(16) unsigned short Blbuf[256 * 64];  // 32KB
  __shared__ float qp_s[NH];
  __shared__ float va_s[NH];
  __shared__ float red[256][4];

  const int sblk = blockIdx.x;
  const int bn   = blockIdx.y;
  const int b    = blockIdx.z;
  const int tid  = threadIdx.x;
  const int w    = tid >> 6;
  const int l    = tid & 63;
  const int rg   = w >> 2;      // 0..1
  const int cg   = w & 3;       // 0..3
  const int l15  = l & 15;
  const int lq   = l >> 4;      // 0..3
  const int asw  = (l15 & 7) << 4;   // read-side swizzle (row&7 == l15&7)

  qp_s[tid] = qproj[b * NH + tid];
  va_s[tid] = vaw[tid];

  // A staging map: thread -> row srow=tid>>1 (0..255), k-half skh=tid&1 (32 floats)
  const int srow = tid >> 1;
  const int skh  = tid & 1;
  const float* agbase = keys + ((size_t)b * NS + sblk * 256 + srow) * NK + skh * 32;
  const int wsw = (srow & 7) << 4;
  char* const Awr = (char*)Albuf + srow * 128;   // byte base of LDS row

  // B staging: per wave 4 x gload16; global src linear == LDS linear (pre-swizzled pack)
  const char* bgbase = (const char*)uapk + (size_t)bn * 524288 + w * 4096 + l * 16;
  char* const Bwr = (char*)Blbuf + w * 4096;     // wave-uniform dest base

  f32x4 acc[8][4];
  #pragma unroll
  for (int i = 0; i < 8; ++i)
    #pragma unroll
    for (int j = 0; j < 4; ++j)
      acc[i][j] = (f32x4){0.f, 0.f, 0.f, 0.f};

  // prologue: issue A(0) loads
  float4 ar0 = *(const float4*)(agbase + 0);
  float4 ar1 = *(const float4*)(agbase + 4);
  float4 ar2 = *(const float4*)(agbase + 8);
  float4 ar3 = *(const float4*)(agbase + 12);
  float4 ar4 = *(const float4*)(agbase + 16);
  float4 ar5 = *(const float4*)(agbase + 20);
  float4 ar6 = *(const float4*)(agbase + 24);
  float4 ar7 = *(const float4*)(agbase + 28);

  for (int kc = 0; kc < 16; ++kc) {
    __syncthreads();   // barrier#1: previous compute done, LDS safe to overwrite
    // issue B loads for this chunk (HW appends lane*16 to dest)
    {
      const char* bg = bgbase + (size_t)kc * 32768;
      #pragma unroll
      for (int j2 = 0; j2 < 4; ++j2)
        gload16(bg + j2 * 1024, Bwr + j2 * 1024);
    }
    // cvt + write A(kc)
    {
      uint4 q0, q1, q2, q3;
      q0.x = pk2(ar0.x, ar0.y); q0.y = pk2(ar0.z, ar0.w);
      q0.z = pk2(ar1.x, ar1.y); q0.w = pk2(ar1.z, ar1.w);
      q1.x = pk2(ar2.x, ar2.y); q1.y = pk2(ar2.z, ar2.w);
      q1.z = pk2(ar3.x, ar3.y); q1.w = pk2(ar3.z, ar3.w);
      q2.x = pk2(ar4.x, ar4.y); q2.y = pk2(ar4.z, ar4.w);
      q2.z = pk2(ar5.x, ar5.y); q2.w = pk2(ar5.z, ar5.w);
      q3.x = pk2(ar6.x, ar6.y); q3.y = pk2(ar6.z, ar6.w);
      q3.z = pk2(ar7.x, ar7.y); q3.w = pk2(ar7.z, ar7.w);
      *(uint4*)(Awr + ((skh * 64 +  0) ^ wsw)) = q0;
      *(uint4*)(Awr + ((skh * 64 + 16) ^ wsw)) = q1;
      *(uint4*)(Awr + ((skh * 64 + 32) ^ wsw)) = q2;
      *(uint4*)(Awr + ((skh * 64 + 48) ^ wsw)) = q3;
    }
    __syncthreads();   // barrier#2: drain — B in LDS, A writes visible

    // issue A loads for kc+1 (latency hides under the MFMA section)
    if (kc < 15) {
      const float* ag = agbase + (kc + 1) * 64;
      ar0 = *(const float4*)(ag + 0);
      ar1 = *(const float4*)(ag + 4);
      ar2 = *(const float4*)(ag + 8);
      ar3 = *(const float4*)(ag + 12);
      ar4 = *(const float4*)(ag + 16);
      ar5 = *(const float4*)(ag + 20);
      ar6 = *(const float4*)(ag + 24);
      ar7 = *(const float4*)(ag + 28);
    }

    const char* Ab = (const char*)Albuf;
    const char* Bb = (const char*)Blbuf;
    #pragma unroll
    for (int h = 0; h < 2; ++h) {
      short8 bf[4];
      #pragma unroll
      for (int ct = 0; ct < 4; ++ct) {
        int nrow = cg * 64 + ct * 16 + l15;
        bf[ct] = *(const short8*)(Bb + nrow * 128 + ((h * 64 + lq * 16) ^ asw));
      }
      #pragma unroll
      for (int rh = 0; rh < 2; ++rh) {
        short8 af[4];
        #pragma unroll
        for (int r4 = 0; r4 < 4; ++r4) {
          int arow = rg * 128 + (rh * 4 + r4) * 16 + l15;
          af[r4] = *(const short8*)(Ab + arow * 128 + ((h * 64 + lq * 16) ^ asw));
        }
        __builtin_amdgcn_s_setprio(1);
        #pragma unroll
        for (int r4 = 0; r4 < 4; ++r4)
          #pragma unroll
          for (int ct = 0; ct < 4; ++ct)
            acc[rh * 4 + r4][ct] =
                __builtin_amdgcn_mfma_f32_16x16x32_bf16(af[r4], bf[ct], acc[rh * 4 + r4][ct], 0, 0, 0);
        __builtin_amdgcn_s_setprio(0);
      }
    }
  }

  // ---- epilogue: partial score over this block's 256 n-cols ----
  #pragma unroll
  for (int rt = 0; rt < 8; ++rt) {
    #pragma unroll
    for (int reg = 0; reg < 4; ++reg) {
      float sum = 0.f;
      #pragma unroll
      for (int ct = 0; ct < 4; ++ct) {
        int gn = bn * 256 + cg * 64 + ct * 16 + l15;
        float x = qp_s[gn] + acc[rt][ct][reg];
        float e = __expf(2.f * x);
        float th = 1.f - __fdividef(2.f, e + 1.f);
        sum += va_s[gn] * th;
      }
      sum += __shfl_xor(sum, 1);
      sum += __shfl_xor(sum, 2);
      sum += __shfl_xor(sum, 4);
      sum += __shfl_xor(sum, 8);
      if (l15 == 0)
        red[rg * 128 + rt * 16 + lq * 4 + reg][cg] = sum;
    }
  }
  __syncthreads();
  if (tid < 256) {
    float s = red[tid][0] + red[tid][1] + red[tid][2] + red[tid][3];
    scores_part[((size_t)bn * NB + b) * NS + sblk * 256 + tid] = s;
  }
}

// ---- kernel 4: softmax over (part0 + part1 + vab) -> attn out ----
__global__ void k_softmax(const float* __restrict__ sp, const float* __restrict__ vab,
                          float* __restrict__ attn) {
  __shared__ float redm[4];
  __shared__ float reds[4];
  int b = blockIdx.x, tid = threadIdx.x;
  const float* r0 = sp + (size_t)b * NS;
  const float* r1 = sp + (size_t)(NB + b) * NS;
  float vb = vab[0];
  float v[16];
  float m = -1e30f;
  #pragma unroll
  for (int i = 0; i < 16; ++i) {
    int idx = i * 256 + tid;
    v[i] = r0[idx] + r1[idx] + vb;
    m = fmaxf(m, v[i]);
  }
  #pragma unroll
  for (int off = 1; off < 64; off <<= 1) m = fmaxf(m, __shfl_xor(m, off));
  if ((tid & 63) == 0) redm[tid >> 6] = m;
  __syncthreads();
  m = fmaxf(fmaxf(redm[0], redm[1]), fmaxf(redm[2], redm[3]));
  float s = 0.f;
  #pragma unroll
  for (int i = 0; i < 16; ++i) { v[i] = expf(v[i] - m); s += v[i]; }
  #pragma unroll
  for (int off = 1; off < 64; off <<= 1) s += __shfl_xor(s, off);
  if ((tid & 63) == 0) reds[tid >> 6] = s;
  __syncthreads();
  s = reds[0] + reds[1] + reds[2] + reds[3];
  float inv = 1.f / s;
  float* o = attn + (size_t)b * NS;
  #pragma unroll
  for (int i = 0; i < 16; ++i) o[i * 256 + tid] = v[i] * inv;
}

// ---- kernel 5: context partials (8 segments of 512 s-rows) ----
__global__ void k_ctx_partial(const float* __restrict__ keys, const float* __restrict__ attn,
                              float* __restrict__ part) {
  __shared__ float w_s[512];
  int b = blockIdx.y, seg = blockIdx.x, tid = threadIdx.x;
  int sbeg = seg * 512;
  w_s[tid] = attn[(size_t)b * NS + sbeg + tid];
  w_s[tid + 256] = attn[(size_t)b * NS + sbeg + 256 + tid];
  __syncthreads();
  const float* kp = keys + ((size_t)b * NS + sbeg) * NK + tid * 4;
  float ax = 0.f, ay = 0.f, az = 0.f, aw = 0.f;
  #pragma unroll 4
  for (int s = 0; s < 512; ++s) {
    float4 kv = *(const float4*)(kp + (size_t)s * NK);
    float wv = w_s[s];
    ax += wv * kv.x; ay += wv * kv.y; az += wv * kv.z; aw += wv * kv.w;
  }
  float4 o; o.x = ax; o.y = ay; o.z = az; o.w = aw;
  *(float4*)(part + ((size_t)(seg * NB + b) << 10) + tid * 4) = o;
}

// ---- kernel 6: reduce 8 segment partials -> context ----
__global__ void k_ctx_reduce(const float* __restrict__ part, float* __restrict__ ctx) {
  int i = blockIdx.x * 256 + threadIdx.x;   // 32768
  int b = i >> 10, c = i & 1023;
  float s = 0.f;
  #pragma unroll
  for (int seg = 0; seg < 8; ++seg) s += part[((size_t)(seg * NB + b) << 10) + c];
  ctx[i] = s;
}

extern "C" void kernel_launch(void* const* d_in, const int* in_sizes, int n_in,
                              void* d_out, int out_size, void* d_ws, size_t ws_size,
                              hipStream_t stream) {
  const float* query = (const float*)d_in[0];
  const float* keys  = (const float*)d_in[1];
  const float* Wa_w  = (const float*)d_in[2];
  const float* Wa_b  = (const float*)d_in[3];
  const float* Ua_w  = (const float*)d_in[4];
  const float* Ua_b  = (const float*)d_in[5];
  const float* Va_w  = (const float*)d_in[6];
  const float* Va_b  = (const float*)d_in[7];

  float* out      = (float*)d_out;
  float* ctx_out  = out;             // [32][1024]
  float* attn_out = out + NB * NK;   // [32][4096]

  unsigned short* ua_pk = (unsigned short*)d_ws;                       // 1 MB
  float* qproj  = (float*)((char*)d_ws + (1u << 20));                  // 64 KB
  float* spart  = (float*)((char*)d_ws + (1u << 20) + (1u << 16));     // 1 MB
  float* part   = (float*)((char*)d_ws + (2u << 20) + (1u << 16));     // 1 MB

  k_ua_pack<<<256, 256, 0, stream>>>(Ua_w, ua_pk);
  k_qproj<<<dim3(4, NB), 128, 0, stream>>>(query, Wa_w, Wa_b, Ua_b, qproj);
  k_scores4<<<dim3(16, 2, NB), 512, 0, stream>>>(keys, ua_pk, qproj, Va_w, spart);
  k_softmax<<<NB, 256, 0, stream>>>(spart, Va_b, attn_out);
  k_ctx_partial<<<dim3(8, NB), 256, 0, stream>>>(keys, attn_out, part);
  k_ctx_reduce<<<NB * NK / 256, 256, 0, stream>>>(part, ctx_out);
}

// Round 5
// 447.242 us; speedup vs baseline: 4.1375x; 4.1375x over previous
//
#include <hip/hip_runtime.h>
#include <hip/hip_bf16.h>
#include <cstdint>
#include <cstddef>

#define NB 32
#define NS 4096
#define NH 512
#define NK 1024   // 2H

typedef __attribute__((ext_vector_type(8))) short short8;
typedef __attribute__((ext_vector_type(4))) float f32x4;

__device__ __forceinline__ unsigned short f2bf_s(float f) {
  union { float f; unsigned u; } x; x.f = f;
  unsigned r = x.u + 0x7fffu + ((x.u >> 16) & 1u);   // RNE bf16
  return (unsigned short)(r >> 16);
}

__device__ __forceinline__ unsigned pk2(float lo, float hi) {
  __hip_bfloat162 h = __float22bfloat162_rn(float2{lo, hi});
  union { __hip_bfloat162 h; unsigned u; } c; c.h = h;
  return c.u;
}

__device__ __forceinline__ void gload16(const void* g, void* l) {
  __builtin_amdgcn_global_load_lds(
      (const __attribute__((address_space(1))) unsigned int*)g,
      (__attribute__((address_space(3))) unsigned int*)l, 16, 0, 0);
}

// ---- kernel 1: pack Ua [512 n][1024 k] f32 -> bf16, pre-swizzled LDS-linear order ----
// layout: [bn(4)][kc(16)][chunk c(1024) of 16B]; c: nloc=c>>3 (0..127), k16=(c&7)^(nloc&7)
// content: bf16 Ua[bn*128+nloc][kc*64 + k16*8 + j], j=0..7
__global__ void k_ua_pack(const float* __restrict__ ua, unsigned short* __restrict__ out) {
  int t = blockIdx.x * 256 + threadIdx.x;   // 65536 chunks of 16B
  int c = t & 1023;
  int kc = (t >> 10) & 15;
  int bn = t >> 14;
  int nloc = c >> 3;
  int k16 = (c & 7) ^ (nloc & 7);
  const float* src = ua + (size_t)(bn * 128 + nloc) * NK + kc * 64 + k16 * 8;
  float4 a = *(const float4*)src;
  float4 b2 = *(const float4*)(src + 4);
  ushort4 o0, o1;
  o0.x = f2bf_s(a.x);  o0.y = f2bf_s(a.y);  o0.z = f2bf_s(a.z);  o0.w = f2bf_s(a.w);
  o1.x = f2bf_s(b2.x); o1.y = f2bf_s(b2.y); o1.z = f2bf_s(b2.z); o1.w = f2bf_s(b2.w);
  ushort4* dst = (ushort4*)(out + (size_t)t * 8);
  dst[0] = o0; dst[1] = o1;
}

// ---- kernel 2: qproj[b][h] = query[b]·Wa_w[h] + Wa_b[h] + Ua_b[h] ----
__global__ void k_qproj(const float* __restrict__ q, const float* __restrict__ ww,
                        const float* __restrict__ wb, const float* __restrict__ ub,
                        float* __restrict__ qp) {
  int b = blockIdx.y;
  int h = blockIdx.x * 128 + threadIdx.x;
  const float* qr = q + b * NH;
  const float* wr = ww + h * NH;
  float acc = 0.f;
  for (int k = 0; k < NH; k += 4) {
    float4 a = *(const float4*)(qr + k);
    float4 c = *(const float4*)(wr + k);
    acc += a.x * c.x + a.y * c.y + a.z * c.z + a.w * c.w;
  }
  qp[b * NH + h] = acc + wb[h] + ub[h];
}

// ---- kernel 3: scores partials, m97 shape: 128x128 tile, 4 waves, 3 blocks/CU ----
// grid (32 sblk, 4 bn, 32 b), 256 thr = 4 waves = 2 rg x 2 cg, wave tile 64x64.
// A single-buffered (reg-stage + cvt_pk), B double-buffered via global_load_lds.
// Per kc: bar#1 -> write A(kc) -> bar#2 -> {issue A(kc+1) regs, issue B(kc+1) gload, 32 MFMA}.
__global__ __launch_bounds__(256, 3)
void k_scores5(const float* __restrict__ keys, const unsigned short* __restrict__ uapk,
               const float* __restrict__ qproj, const float* __restrict__ vaw,
               float* __restrict__ scores_part) {
  __shared__ alignas(16) unsigned short Albuf[128 * 64];     // 16KB
  __shared__ alignas(16) unsigned short Blbuf[2][128 * 64];  // 2 x 16KB
  __shared__ float qp_s[128];
  __shared__ float va_s[128];
  __shared__ float red[128][2];

  const int sblk = blockIdx.x;
  const int bn   = blockIdx.y;
  const int b    = blockIdx.z;
  const int tid  = threadIdx.x;
  const int w    = tid >> 6;
  const int l    = tid & 63;
  const int rg   = w >> 1;      // 0..1
  const int cg   = w & 1;       // 0..1
  const int l15  = l & 15;
  const int lq   = l >> 4;      // 0..3
  const int asw  = (l15 & 7) << 4;   // read-side swizzle (row&7 == l15&7)

  if (tid < 128) {
    qp_s[tid] = qproj[b * NH + bn * 128 + tid];
    va_s[tid] = vaw[bn * 128 + tid];
  }

  // A staging map: thread -> row srow=tid>>1 (0..127), k-half skh=tid&1 (32 floats)
  const int srow = tid >> 1;
  const int skh  = tid & 1;
  const float* agbase = keys + ((size_t)b * NS + sblk * 128 + srow) * NK + skh * 32;
  const int wsw = (srow & 7) << 4;
  char* const Awr = (char*)Albuf + srow * 128;   // byte base of LDS row

  // B staging: per wave 4 x gload16 (4KB); global src linear == LDS linear (pre-swizzled)
  const char* bgbase = (const char*)uapk + (size_t)bn * 262144 + w * 4096 + l * 16;

  f32x4 acc[4][4];
  #pragma unroll
  for (int i = 0; i < 4; ++i)
    #pragma unroll
    for (int j = 0; j < 4; ++j)
      acc[i][j] = (f32x4){0.f, 0.f, 0.f, 0.f};

  // prologue: issue A(0) reg loads and B(0) gload_lds into buf 0
  float4 ar0 = *(const float4*)(agbase + 0);
  float4 ar1 = *(const float4*)(agbase + 4);
  float4 ar2 = *(const float4*)(agbase + 8);
  float4 ar3 = *(const float4*)(agbase + 12);
  float4 ar4 = *(const float4*)(agbase + 16);
  float4 ar5 = *(const float4*)(agbase + 20);
  float4 ar6 = *(const float4*)(agbase + 24);
  float4 ar7 = *(const float4*)(agbase + 28);
  #pragma unroll
  for (int j2 = 0; j2 < 4; ++j2)
    gload16(bgbase + j2 * 1024, (char*)&Blbuf[0][0] + w * 4096 + j2 * 1024);

  for (int kc = 0; kc < 16; ++kc) {
    const int cur = kc & 1;
    __syncthreads();   // bar#1: previous MFMA done, Albuf safe to overwrite
    // cvt + write A(kc)
    {
      uint4 q0, q1, q2, q3;
      q0.x = pk2(ar0.x, ar0.y); q0.y = pk2(ar0.z, ar0.w);
      q0.z = pk2(ar1.x, ar1.y); q0.w = pk2(ar1.z, ar1.w);
      q1.x = pk2(ar2.x, ar2.y); q1.y = pk2(ar2.z, ar2.w);
      q1.z = pk2(ar3.x, ar3.y); q1.w = pk2(ar3.z, ar3.w);
      q2.x = pk2(ar4.x, ar4.y); q2.y = pk2(ar4.z, ar4.w);
      q2.z = pk2(ar5.x, ar5.y); q2.w = pk2(ar5.z, ar5.w);
      q3.x = pk2(ar6.x, ar6.y); q3.y = pk2(ar6.z, ar6.w);
      q3.z = pk2(ar7.x, ar7.y); q3.w = pk2(ar7.z, ar7.w);
      *(uint4*)(Awr + ((skh * 64 +  0) ^ wsw)) = q0;
      *(uint4*)(Awr + ((skh * 64 + 16) ^ wsw)) = q1;
      *(uint4*)(Awr + ((skh * 64 + 32) ^ wsw)) = q2;
      *(uint4*)(Awr + ((skh * 64 + 48) ^ wsw)) = q3;
    }
    __syncthreads();   // bar#2: A visible; B(kc) long since landed in Blbuf[cur]

    if (kc < 15) {
      // issue A(kc+1) reg loads — consumed at next bar#1; hides under MFMA
      const float* ag = agbase + (kc + 1) * 64;
      ar0 = *(const float4*)(ag + 0);
      ar1 = *(const float4*)(ag + 4);
      ar2 = *(const float4*)(ag + 8);
      ar3 = *(const float4*)(ag + 12);
      ar4 = *(const float4*)(ag + 16);
      ar5 = *(const float4*)(ag + 20);
      ar6 = *(const float4*)(ag + 24);
      ar7 = *(const float4*)(ag + 28);
      // issue B(kc+1) gload_lds into the other buffer — drains at next bar#2
      const char* bg = bgbase + (size_t)(kc + 1) * 16384;
      #pragma unroll
      for (int j2 = 0; j2 < 4; ++j2)
        gload16(bg + j2 * 1024, (char*)&Blbuf[cur ^ 1][0] + w * 4096 + j2 * 1024);
    }

    const char* Ab = (const char*)Albuf;
    const char* Bb = (const char*)&Blbuf[cur][0];
    #pragma unroll
    for (int h = 0; h < 2; ++h) {
      short8 bf[4];
      #pragma unroll
      for (int ct = 0; ct < 4; ++ct) {
        int nrow = cg * 64 + ct * 16 + l15;
        bf[ct] = *(const short8*)(Bb + nrow * 128 + ((h * 64 + lq * 16) ^ asw));
      }
      short8 af[4];
      #pragma unroll
      for (int r4 = 0; r4 < 4; ++r4) {
        int arow = rg * 64 + r4 * 16 + l15;
        af[r4] = *(const short8*)(Ab + arow * 128 + ((h * 64 + lq * 16) ^ asw));
      }
      __builtin_amdgcn_s_setprio(1);
      #pragma unroll
      for (int r4 = 0; r4 < 4; ++r4)
        #pragma unroll
        for (int ct = 0; ct < 4; ++ct)
          acc[r4][ct] =
              __builtin_amdgcn_mfma_f32_16x16x32_bf16(af[r4], bf[ct], acc[r4][ct], 0, 0, 0);
      __builtin_amdgcn_s_setprio(0);
    }
  }

  // ---- epilogue: partial score over this block's 128 n-cols ----
  #pragma unroll
  for (int r4 = 0; r4 < 4; ++r4) {
    #pragma unroll
    for (int reg = 0; reg < 4; ++reg) {
      float sum = 0.f;
      #pragma unroll
      for (int ct = 0; ct < 4; ++ct) {
        int gn = cg * 64 + ct * 16 + l15;
        float x = qp_s[gn] + acc[r4][ct][reg];
        float e = __expf(2.f * x);
        float th = 1.f - __fdividef(2.f, e + 1.f);
        sum += va_s[gn] * th;
      }
      sum += __shfl_xor(sum, 1);
      sum += __shfl_xor(sum, 2);
      sum += __shfl_xor(sum, 4);
      sum += __shfl_xor(sum, 8);
      if (l15 == 0)
        red[rg * 64 + r4 * 16 + lq * 4 + reg][cg] = sum;
    }
  }
  __syncthreads();
  if (tid < 128) {
    float s = red[tid][0] + red[tid][1];
    scores_part[((size_t)bn * NB + b) * NS + sblk * 128 + tid] = s;
  }
}

// ---- kernel 4: softmax over (sum of 4 partials + vab) -> attn out ----
__global__ void k_softmax(const float* __restrict__ sp, const float* __restrict__ vab,
                          float* __restrict__ attn) {
  __shared__ float redm[4];
  __shared__ float reds[4];
  int b = blockIdx.x, tid = threadIdx.x;
  const float* r0 = sp + (size_t)b * NS;
  const float* r1 = sp + (size_t)(NB + b) * NS;
  const float* r2 = sp + (size_t)(2 * NB + b) * NS;
  const float* r3 = sp + (size_t)(3 * NB + b) * NS;
  float vb = vab[0];
  float v[16];
  float m = -1e30f;
  #pragma unroll
  for (int i = 0; i < 16; ++i) {
    int idx = i * 256 + tid;
    v[i] = (r0[idx] + r1[idx]) + (r2[idx] + r3[idx]) + vb;
    m = fmaxf(m, v[i]);
  }
  #pragma unroll
  for (int off = 1; off < 64; off <<= 1) m = fmaxf(m, __shfl_xor(m, off));
  if ((tid & 63) == 0) redm[tid >> 6] = m;
  __syncthreads();
  m = fmaxf(fmaxf(redm[0], redm[1]), fmaxf(redm[2], redm[3]));
  float s = 0.f;
  #pragma unroll
  for (int i = 0; i < 16; ++i) { v[i] = expf(v[i] - m); s += v[i]; }
  #pragma unroll
  for (int off = 1; off < 64; off <<= 1) s += __shfl_xor(s, off);
  if ((tid & 63) == 0) reds[tid >> 6] = s;
  __syncthreads();
  s = reds[0] + reds[1] + reds[2] + reds[3];
  float inv = 1.f / s;
  float* o = attn + (size_t)b * NS;
  #pragma unroll
  for (int i = 0; i < 16; ++i) o[i * 256 + tid] = v[i] * inv;
}

// ---- kernel 5: context partials (8 segments of 512 s-rows) ----
__global__ void k_ctx_partial(const float* __restrict__ keys, const float* __restrict__ attn,
                              float* __restrict__ part) {
  __shared__ float w_s[512];
  int b = blockIdx.y, seg = blockIdx.x, tid = threadIdx.x;
  int sbeg = seg * 512;
  w_s[tid] = attn[(size_t)b * NS + sbeg + tid];
  w_s[tid + 256] = attn[(size_t)b * NS + sbeg + 256 + tid];
  __syncthreads();
  const float* kp = keys + ((size_t)b * NS + sbeg) * NK + tid * 4;
  float ax = 0.f, ay = 0.f, az = 0.f, aw = 0.f;
  #pragma unroll 4
  for (int s = 0; s < 512; ++s) {
    float4 kv = *(const float4*)(kp + (size_t)s * NK);
    float wv = w_s[s];
    ax += wv * kv.x; ay += wv * kv.y; az += wv * kv.z; aw += wv * kv.w;
  }
  float4 o; o.x = ax; o.y = ay; o.z = az; o.w = aw;
  *(float4*)(part + ((size_t)(seg * NB + b) << 10) + tid * 4) = o;
}

// ---- kernel 6: reduce 8 segment partials -> context ----
__global__ void k_ctx_reduce(const float* __restrict__ part, float* __restrict__ ctx) {
  int i = blockIdx.x * 256 + threadIdx.x;   // 32768
  int b = i >> 10, c = i & 1023;
  float s = 0.f;
  #pragma unroll
  for (int seg = 0; seg < 8; ++seg) s += part[((size_t)(seg * NB + b) << 10) + c];
  ctx[i] = s;
}

extern "C" void kernel_launch(void* const* d_in, const int* in_sizes, int n_in,
                              void* d_out, int out_size, void* d_ws, size_t ws_size,
                              hipStream_t stream) {
  const float* query = (const float*)d_in[0];
  const float* keys  = (const float*)d_in[1];
  const float* Wa_w  = (const float*)d_in[2];
  const float* Wa_b  = (const float*)d_in[3];
  const float* Ua_w  = (const float*)d_in[4];
  const float* Ua_b  = (const float*)d_in[5];
  const float* Va_w  = (const float*)d_in[6];
  const float* Va_b  = (const float*)d_in[7];

  float* out      = (float*)d_out;
  float* ctx_out  = out;             // [32][1024]
  float* attn_out = out + NB * NK;   // [32][4096]

  unsigned short* ua_pk = (unsigned short*)d_ws;                       // 1 MB
  float* qproj  = (float*)((char*)d_ws + (1u << 20));                  // 64 KB
  float* spart  = (float*)((char*)d_ws + (1u << 20) + (1u << 16));     // 2 MB (4 partials)
  float* part   = spart;  // 1 MB, aliases spart (dead after k_softmax)

  k_ua_pack<<<256, 256, 0, stream>>>(Ua_w, ua_pk);
  k_qproj<<<dim3(4, NB), 128, 0, stream>>>(query, Wa_w, Wa_b, Ua_b, qproj);
  k_scores5<<<dim3(32, 4, NB), 256, 0, stream>>>(keys, ua_pk, qproj, Va_w, spart);
  k_softmax<<<NB, 256, 0, stream>>>(spart, Va_b, attn_out);
  k_ctx_partial<<<dim3(8, NB), 256, 0, stream>>>(keys, attn_out, part);
  k_ctx_reduce<<<NB * NK / 256, 256, 0, stream>>>(part, ctx_out);
}

// Round 6
// 436.204 us; speedup vs baseline: 4.2422x; 1.0253x over previous
//
#include <hip/hip_runtime.h>
#include <hip/hip_bf16.h>
#include <cstdint>
#include <cstddef>

#define NB 32
#define NS 4096
#define NH 512
#define NK 1024   // 2H

typedef __attribute__((ext_vector_type(8))) short short8;
typedef __attribute__((ext_vector_type(4))) float f32x4;

__device__ __forceinline__ unsigned short f2bf_s(float f) {
  union { float f; unsigned u; } x; x.f = f;
  unsigned r = x.u + 0x7fffu + ((x.u >> 16) & 1u);   // RNE bf16
  return (unsigned short)(r >> 16);
}

__device__ __forceinline__ unsigned pk2(float lo, float hi) {
  __hip_bfloat162 h = __float22bfloat162_rn(float2{lo, hi});
  union { __hip_bfloat162 h; unsigned u; } c; c.h = h;
  return c.u;
}

__device__ __forceinline__ void gload16(const void* g, void* l) {
  __builtin_amdgcn_global_load_lds(
      (const __attribute__((address_space(1))) unsigned int*)g,
      (__attribute__((address_space(3))) unsigned int*)l, 16, 0, 0);
}

// ---- kernel 1: pack Ua [512 n][1024 k] f32 -> bf16, pre-swizzled LDS-linear order ----
// layout: [bn(4)][kc(16)][chunk c(1024) of 16B]; c: nloc=c>>3 (0..127), k16=(c&7)^(nloc&7)
__global__ void k_ua_pack(const float* __restrict__ ua, unsigned short* __restrict__ out) {
  int t = blockIdx.x * 256 + threadIdx.x;   // 65536 chunks of 16B
  int c = t & 1023;
  int kc = (t >> 10) & 15;
  int bn = t >> 14;
  int nloc = c >> 3;
  int k16 = (c & 7) ^ (nloc & 7);
  const float* src = ua + (size_t)(bn * 128 + nloc) * NK + kc * 64 + k16 * 8;
  float4 a = *(const float4*)src;
  float4 b2 = *(const float4*)(src + 4);
  ushort4 o0, o1;
  o0.x = f2bf_s(a.x);  o0.y = f2bf_s(a.y);  o0.z = f2bf_s(a.z);  o0.w = f2bf_s(a.w);
  o1.x = f2bf_s(b2.x); o1.y = f2bf_s(b2.y); o1.z = f2bf_s(b2.z); o1.w = f2bf_s(b2.w);
  ushort4* dst = (ushort4*)(out + (size_t)t * 8);
  dst[0] = o0; dst[1] = o1;
}

// ---- kernel 2: qproj[b][h] = query[b]·Wa_w[h] + Wa_b[h] + Ua_b[h] ----
__global__ void k_qproj(const float* __restrict__ q, const float* __restrict__ ww,
                        const float* __restrict__ wb, const float* __restrict__ ub,
                        float* __restrict__ qp) {
  int b = blockIdx.y;
  int h = blockIdx.x * 128 + threadIdx.x;
  const float* qr = q + b * NH;
  const float* wr = ww + h * NH;
  float acc = 0.f;
  for (int k = 0; k < NH; k += 4) {
    float4 a = *(const float4*)(qr + k);
    float4 c = *(const float4*)(wr + k);
    acc += a.x * c.x + a.y * c.y + a.z * c.z + a.w * c.w;
  }
  qp[b * NH + h] = acc + wb[h] + ub[h];
}

// ---- kernel 3: scores partials; wave-private A (global->reg->MFMA), B dbuf in LDS ----
// grid (32 sblk, 4 bn, 32 b), 256 thr = 4 waves; wave tile 32 rows x 128 cols.
// One raw s_barrier per K-chunk; counted vmcnt (never 0 mid-loop); B issued 2 iters ahead.
__global__ __launch_bounds__(256, 3)
void k_scores6(const float* __restrict__ keys, const unsigned short* __restrict__ uapk,
               const float* __restrict__ qproj, const float* __restrict__ vaw,
               float* __restrict__ scores_part) {
  __shared__ alignas(16) unsigned short Blbuf[2][128 * 64];  // 2 x 16KB
  __shared__ float qp_s[128];
  __shared__ float va_s[128];

  const int sblk = blockIdx.x;
  const int bn   = blockIdx.y;
  const int b    = blockIdx.z;
  const int tid  = threadIdx.x;
  const int w    = tid >> 6;
  const int l    = tid & 63;
  const int l15  = l & 15;
  const int lq   = l >> 4;      // 0..3
  const int asw  = (l15 & 7) << 4;   // read-side swizzle (row&7 == l15&7)

  if (tid < 128) {
    qp_s[tid] = qproj[b * NH + bn * 128 + tid];
    va_s[tid] = vaw[bn * 128 + tid];
  }
  __syncthreads();   // one-time; before any prefetch is in flight

  // A: wave-private rows w*32 + rt*16 + l15; per lane k-base lq*8
  const float* aptr = keys + ((size_t)b * NS + sblk * 128 + w * 32 + l15) * NK + lq * 8;
  // B staging: per wave 4 x gload16 (4KB); global src linear == LDS linear (pre-swizzled)
  const char* bgbase = (const char*)uapk + (size_t)bn * 262144 + w * 4096 + l * 16;

  f32x4 acc[2][8];
  #pragma unroll
  for (int i = 0; i < 2; ++i)
    #pragma unroll
    for (int j = 0; j < 8; ++j)
      acc[i][j] = (f32x4){0.f, 0.f, 0.f, 0.f};

  // prologue: B(0)->buf0, B(1)->buf1, A(0)->regs
  #pragma unroll
  for (int j2 = 0; j2 < 4; ++j2)
    gload16(bgbase + j2 * 1024, (char*)&Blbuf[0][0] + w * 4096 + j2 * 1024);
  #pragma unroll
  for (int j2 = 0; j2 < 4; ++j2)
    gload16(bgbase + 16384 + j2 * 1024, (char*)&Blbuf[1][0] + w * 4096 + j2 * 1024);

  float4 ca[8];
  #pragma unroll
  for (int rt = 0; rt < 2; ++rt)
    #pragma unroll
    for (int kk = 0; kk < 2; ++kk) {
      const float* p = aptr + rt * 16 * NK + kk * 32;
      ca[(rt * 2 + kk) * 2 + 0] = *(const float4*)p;
      ca[(rt * 2 + kk) * 2 + 1] = *(const float4*)(p + 4);
    }

  #pragma unroll
  for (int kc = 0; kc < 16; ++kc) {
    const int cur = kc & 1;
    // issue A(kc+1) f32 loads (consumed next iter; latency hidden under this iter)
    float4 na[8];
    if (kc < 15) {
      const float* ag = aptr + (kc + 1) * 64;
      #pragma unroll
      for (int rt = 0; rt < 2; ++rt)
        #pragma unroll
        for (int kk = 0; kk < 2; ++kk) {
          const float* p = ag + rt * 16 * NK + kk * 32;
          na[(rt * 2 + kk) * 2 + 0] = *(const float4*)p;
          na[(rt * 2 + kk) * 2 + 1] = *(const float4*)(p + 4);
        }
    }
    // counted wait: B(kc) landed (allow B(kc+1)=4 + A(kc+1)=8 in flight). Never 0 mid-loop.
    if (kc < 15) asm volatile("s_waitcnt vmcnt(12)" ::: "memory");
    else         asm volatile("s_waitcnt vmcnt(0)" ::: "memory");
    __builtin_amdgcn_sched_barrier(0);

    // cvt A(kc) -> bf16 fragments (compiler adds its own precise wait for ca)
    short8 af[2][2];
    #pragma unroll
    for (int rt = 0; rt < 2; ++rt)
      #pragma unroll
      for (int kk = 0; kk < 2; ++kk) {
        float4 a0 = ca[(rt * 2 + kk) * 2 + 0];
        float4 a1 = ca[(rt * 2 + kk) * 2 + 1];
        uint4 q;
        q.x = pk2(a0.x, a0.y); q.y = pk2(a0.z, a0.w);
        q.z = pk2(a1.x, a1.y); q.w = pk2(a1.z, a1.w);
        union { uint4 u; short8 s; } cvt; cvt.u = q;
        af[rt][kk] = cvt.s;
      }

    const char* Bb = (const char*)&Blbuf[cur][0];
    #pragma unroll
    for (int kk = 0; kk < 2; ++kk) {
      short8 bf[8];
      #pragma unroll
      for (int ct = 0; ct < 8; ++ct)
        bf[ct] = *(const short8*)(Bb + (ct * 16 + l15) * 128 + ((kk * 64 + lq * 16) ^ asw));
      __builtin_amdgcn_s_setprio(1);
      #pragma unroll
      for (int ct = 0; ct < 8; ++ct)
        #pragma unroll
        for (int rt = 0; rt < 2; ++rt)
          acc[rt][ct] =
              __builtin_amdgcn_mfma_f32_16x16x32_bf16(af[rt][kk], bf[ct], acc[rt][ct], 0, 0, 0);
      __builtin_amdgcn_s_setprio(0);
    }

    // all my ds_reads complete before crossing the barrier (B(kc+2) will overwrite this buf)
    asm volatile("s_waitcnt lgkmcnt(0)" ::: "memory");
    __builtin_amdgcn_sched_barrier(0);
    __builtin_amdgcn_s_barrier();

    if (kc < 14) {   // issue B(kc+2) into the buffer just freed by ALL waves
      const char* bg = bgbase + (size_t)(kc + 2) * 16384;
      #pragma unroll
      for (int j2 = 0; j2 < 4; ++j2)
        gload16(bg + j2 * 1024, (char*)&Blbuf[cur][0] + w * 4096 + j2 * 1024);
    }
    if (kc < 15) {
      #pragma unroll
      for (int i = 0; i < 8; ++i) ca[i] = na[i];
    }
  }

  // ---- epilogue: wave owns full 128 cols of its 32 rows -> direct global write ----
  #pragma unroll
  for (int rt = 0; rt < 2; ++rt) {
    #pragma unroll
    for (int reg = 0; reg < 4; ++reg) {
      float sum = 0.f;
      #pragma unroll
      for (int ct = 0; ct < 8; ++ct) {
        int col = ct * 16 + l15;
        float x = qp_s[col] + acc[rt][ct][reg];
        float e = __expf(2.f * x);
        float th = 1.f - __fdividef(2.f, e + 1.f);
        sum += va_s[col] * th;
      }
      sum += __shfl_xor(sum, 1);
      sum += __shfl_xor(sum, 2);
      sum += __shfl_xor(sum, 4);
      sum += __shfl_xor(sum, 8);
      if (l15 == 0)
        scores_part[((size_t)bn * NB + b) * NS + sblk * 128 + w * 32 + rt * 16 + lq * 4 + reg] = sum;
    }
  }
}

// ---- kernel 4: softmax over (sum of 4 partials + vab) -> attn out ----
__global__ void k_softmax(const float* __restrict__ sp, const float* __restrict__ vab,
                          float* __restrict__ attn) {
  __shared__ float redm[4];
  __shared__ float reds[4];
  int b = blockIdx.x, tid = threadIdx.x;
  const float* r0 = sp + (size_t)b * NS;
  const float* r1 = sp + (size_t)(NB + b) * NS;
  const float* r2 = sp + (size_t)(2 * NB + b) * NS;
  const float* r3 = sp + (size_t)(3 * NB + b) * NS;
  float vb = vab[0];
  float v[16];
  float m = -1e30f;
  #pragma unroll
  for (int i = 0; i < 16; ++i) {
    int idx = i * 256 + tid;
    v[i] = (r0[idx] + r1[idx]) + (r2[idx] + r3[idx]) + vb;
    m = fmaxf(m, v[i]);
  }
  #pragma unroll
  for (int off = 1; off < 64; off <<= 1) m = fmaxf(m, __shfl_xor(m, off));
  if ((tid & 63) == 0) redm[tid >> 6] = m;
  __syncthreads();
  m = fmaxf(fmaxf(redm[0], redm[1]), fmaxf(redm[2], redm[3]));
  float s = 0.f;
  #pragma unroll
  for (int i = 0; i < 16; ++i) { v[i] = expf(v[i] - m); s += v[i]; }
  #pragma unroll
  for (int off = 1; off < 64; off <<= 1) s += __shfl_xor(s, off);
  if ((tid & 63) == 0) reds[tid >> 6] = s;
  __syncthreads();
  s = reds[0] + reds[1] + reds[2] + reds[3];
  float inv = 1.f / s;
  float* o = attn + (size_t)b * NS;
  #pragma unroll
  for (int i = 0; i < 16; ++i) o[i * 256 + tid] = v[i] * inv;
}

// ---- kernel 5: context partials (8 segments of 512 s-rows) ----
__global__ void k_ctx_partial(const float* __restrict__ keys, const float* __restrict__ attn,
                              float* __restrict__ part) {
  __shared__ float w_s[512];
  int b = blockIdx.y, seg = blockIdx.x, tid = threadIdx.x;
  int sbeg = seg * 512;
  w_s[tid] = attn[(size_t)b * NS + sbeg + tid];
  w_s[tid + 256] = attn[(size_t)b * NS + sbeg + 256 + tid];
  __syncthreads();
  const float* kp = keys + ((size_t)b * NS + sbeg) * NK + tid * 4;
  float ax = 0.f, ay = 0.f, az = 0.f, aw = 0.f;
  #pragma unroll 4
  for (int s = 0; s < 512; ++s) {
    float4 kv = *(const float4*)(kp + (size_t)s * NK);
    float wv = w_s[s];
    ax += wv * kv.x; ay += wv * kv.y; az += wv * kv.z; aw += wv * kv.w;
  }
  float4 o; o.x = ax; o.y = ay; o.z = az; o.w = aw;
  *(float4*)(part + ((size_t)(seg * NB + b) << 10) + tid * 4) = o;
}

// ---- kernel 6: reduce 8 segment partials -> context ----
__global__ void k_ctx_reduce(const float* __restrict__ part, float* __restrict__ ctx) {
  int i = blockIdx.x * 256 + threadIdx.x;   // 32768
  int b = i >> 10, c = i & 1023;
  float s = 0.f;
  #pragma unroll
  for (int seg = 0; seg < 8; ++seg) s += part[((size_t)(seg * NB + b) << 10) + c];
  ctx[i] = s;
}

extern "C" void kernel_launch(void* const* d_in, const int* in_sizes, int n_in,
                              void* d_out, int out_size, void* d_ws, size_t ws_size,
                              hipStream_t stream) {
  const float* query = (const float*)d_in[0];
  const float* keys  = (const float*)d_in[1];
  const float* Wa_w  = (const float*)d_in[2];
  const float* Wa_b  = (const float*)d_in[3];
  const float* Ua_w  = (const float*)d_in[4];
  const float* Ua_b  = (const float*)d_in[5];
  const float* Va_w  = (const float*)d_in[6];
  const float* Va_b  = (const float*)d_in[7];

  float* out      = (float*)d_out;
  float* ctx_out  = out;             // [32][1024]
  float* attn_out = out + NB * NK;   // [32][4096]

  unsigned short* ua_pk = (unsigned short*)d_ws;                       // 1 MB
  float* qproj  = (float*)((char*)d_ws + (1u << 20));                  // 64 KB
  float* spart  = (float*)((char*)d_ws + (1u << 20) + (1u << 16));     // 2 MB (4 partials)
  float* part   = spart;  // 1 MB, aliases spart (dead after k_softmax)

  k_ua_pack<<<256, 256, 0, stream>>>(Ua_w, ua_pk);
  k_qproj<<<dim3(4, NB), 128, 0, stream>>>(query, Wa_w, Wa_b, Ua_b, qproj);
  k_scores6<<<dim3(32, 4, NB), 256, 0, stream>>>(keys, ua_pk, qproj, Va_w, spart);
  k_softmax<<<NB, 256, 0, stream>>>(spart, Va_b, attn_out);
  k_ctx_partial<<<dim3(8, NB), 256, 0, stream>>>(keys, attn_out, part);
  k_ctx_reduce<<<NB * NK / 256, 256, 0, stream>>>(part, ctx_out);
}